// Round 9
// baseline (269.577 us; speedup 1.0000x reference)
//
#include <hip/hip_runtime.h>
#include <hip/hip_bf16.h>
#include <hip/hip_fp16.h>

#define NEG_INF -1000000000.0f

typedef __attribute__((ext_vector_type(8))) short bf16x8;
typedef __attribute__((ext_vector_type(4))) float f32x4;

__device__ __forceinline__ unsigned short f2bf(float f) {
    unsigned int u = __float_as_uint(f);
    u += 0x7FFFu + ((u >> 16) & 1u);
    return (unsigned short)(u >> 16);
}

__device__ __forceinline__ float h2f(unsigned short us) {
    __half h;
    __builtin_memcpy(&h, &us, 2);
    return __half2float(h);
}

#define GLOAD_LDS16(gp, lp)                                                  \
    __builtin_amdgcn_global_load_lds(                                        \
        (const __attribute__((address_space(1))) void*)(gp),                 \
        (__attribute__((address_space(3))) void*)(lp), 16, 0, 0)

// 256x256-tile BT-form bf16 GEMM, BK=64, 512 threads = 8 waves (2Mx4N),
// 4 phases per K-tile (2 barriers/phase), double-buffered 128 KiB LDS,
// counted-vmcnt pipeline (never 0 in main loop), T2 XOR swizzle, T5 setprio.
// C[m][n] = sum_k A[m][k]*B[n][k].
// EPI: 4 = merged projections: work-id < 256 -> Q tile ([16384x1024], *1/32);
//          else KV tile (gathered A rows, early-exit M >= ncp[bz];
//          col<1024 -> Kc row-store, else -> Vtc transposed store)
//      1 = scores compact (fp16 out; early-exit N-tiles >= ncp[bz])
//      2 = PV (fp32 out; runtime K = ncp[bz])
template<int EPI>
__global__ __launch_bounds__(512, 2)
void gemm256(const unsigned short* __restrict__ A, const unsigned short* __restrict__ B,
             void* __restrict__ C0, void* __restrict__ C1, void* __restrict__ C2,
             const float* __restrict__ b0, const float* __restrict__ b1,
             const float* __restrict__ b2,
             const int* __restrict__ cidx, const int* __restrict__ ncinfo,
             int K, long lda, long ldb, long ldc,
             long batchA, long batchB, long batchC,
             int gx, int gy)
{
    __shared__ unsigned short As[2][16384];
    __shared__ unsigned short Bs[2][16384];

    // T1: bijective XCD swizzle (all launched grids are % 8 == 0)
    int bid = blockIdx.x;
    bid = (bid & 7) * ((int)gridDim.x >> 3) + (bid >> 3);

    int bz = 0, bm, bn;
    bool qpath = false;
    if (EPI == 4) {
        if (bid < 256) {                    // Q projection tile
            qpath = true;
            bm = (bid >> 2) * 256;          // over 16384 rows
            bn = (bid & 3) * 256;           // over 1024 cols
        } else {                            // KV projection tile
            const int kid = bid - 256;
            bz = kid >> 6;
            const int r2 = kid & 63;
            bm = (r2 >> 3) * 256;           // compacted rows
            bn = (r2 & 7) * 256;            // 0..2047: K | V
            if (bm >= ncinfo[8 + bz]) return;
        }
    } else {
        const int gxy = gx * gy;
        bz = bid / gxy;
        const int rem = bid - bz * gxy;
        const int tm = rem / gy;
        bm = tm * 256;
        bn = (rem - tm * gy) * 256;
        if (EPI == 1) { if (bn >= ncinfo[8 + bz]) return; }
    }

    const int t    = threadIdx.x;
    const int lane = t & 63;
    const int w    = t >> 6;
    const int wr   = w >> 2;          // wave row 0..1 (128 rows each)
    const int wc   = w & 3;           // wave col 0..3 (64 cols each)
    const int lr   = lane & 15;
    const int lkg  = lane >> 4;       // 0..3
    const int sx8  = (lr & 7) * 8;    // T2 read-side XOR (row parity, elems)
    const int e0   = (lkg * 8) ^ sx8; // kk=0 chunk; kk=1 is e0^32

    // staging: thread t -> row tr (of 64-row load region), swizzled col chunk
    const int tr  = t >> 3;
    const int tcs = ((t & 7) ^ (tr & 7)) * 8;    // pre-swizzled source col (elems)
    const int wb512 = w * 512;                   // wave-uniform LDS elem offset

    // per-L A row base pointers + B base
    const unsigned short* ApG[4];
    const unsigned short* Bb;
    if (EPI == 4) {
        if (qpath) {
#pragma unroll
            for (int L = 0; L < 4; ++L)
                ApG[L] = A + (size_t)(bm + L * 64 + tr) * lda + tcs;
            Bb = B + (size_t)(bn + tr) * ldb + tcs;            // Wq rows
        } else {
#pragma unroll
            for (int L = 0; L < 4; ++L) {
                const int rr = cidx[bz * 2048 + bm + L * 64 + tr];
                ApG[L] = A + ((size_t)bz * 2048 + rr) * lda + tcs;
            }
            Bb = B + (size_t)(1024 + bn + tr) * ldb + tcs;     // Wk|Wv rows
        }
    } else {
        const unsigned short* Ab = A + (size_t)bz * (size_t)batchA
                                     + (size_t)(bm + tr) * lda + tcs;
#pragma unroll
        for (int L = 0; L < 4; ++L) ApG[L] = Ab + (size_t)L * 64 * lda;
        Bb = B + (size_t)bz * (size_t)batchB + (size_t)(bn + tr) * ldb + tcs;
    }

    const int Kd = (EPI == 2) ? ncinfo[8 + bz] : K;

#define ST_A(nb, L, kt) GLOAD_LDS16(ApG[L] + (kt), &As[nb][(L) * 4096 + wb512])
#define ST_B(nb, L, kt) GLOAD_LDS16(Bb + (size_t)(L) * 64 * ldb + (kt), &Bs[nb][(L) * 4096 + wb512])

    f32x4 acc[8][4];
#pragma unroll
    for (int i = 0; i < 8; ++i)
#pragma unroll
        for (int j = 0; j < 4; ++j)
            acc[i][j] = f32x4{0.f, 0.f, 0.f, 0.f};

    // ---- prologue: stage tile 0 (needed-first order), leave A1,A3 in flight ----
    ST_B(0, 0, 0); ST_B(0, 1, 0); ST_B(0, 2, 0); ST_B(0, 3, 0);
    ST_A(0, 0, 0); ST_A(0, 2, 0); ST_A(0, 1, 0); ST_A(0, 3, 0);
    asm volatile("s_waitcnt vmcnt(2)" ::: "memory");
    __builtin_amdgcn_s_barrier();

    bf16x8 a[2][2], b[4][2];

#define READ_B(BUF)                                                          \
    _Pragma("unroll") for (int j = 0; j < 4; ++j) {                          \
        const int Rb = wc * 64 + j * 16 + lr;                                \
        b[j][0] = *(const bf16x8*)&Bs[BUF][Rb * 64 + e0];                    \
        b[j][1] = *(const bf16x8*)&Bs[BUF][Rb * 64 + (e0 ^ 32)];             \
    }

#define LOAD_A(BUF, qp)                                                      \
    _Pragma("unroll") for (int i2 = 0; i2 < 2; ++i2) {                       \
        const int Ra = wr * 128 + (qp) * 32 + i2 * 16 + lr;                  \
        a[i2][0] = *(const bf16x8*)&As[BUF][Ra * 64 + e0];                   \
        a[i2][1] = *(const bf16x8*)&As[BUF][Ra * 64 + (e0 ^ 32)];            \
    }

#define MFMA_Q(qp)                                                           \
    __builtin_amdgcn_s_setprio(1);                                           \
    _Pragma("unroll") for (int kk = 0; kk < 2; ++kk)                         \
    _Pragma("unroll") for (int i2 = 0; i2 < 2; ++i2)                         \
    _Pragma("unroll") for (int j = 0; j < 4; ++j)                            \
        acc[(qp) * 2 + i2][j] = __builtin_amdgcn_mfma_f32_16x16x32_bf16(     \
            a[i2][kk], b[j][kk], acc[(qp) * 2 + i2][j], 0, 0, 0);            \
    __builtin_amdgcn_s_setprio(0);

#define TILE(BUF, STAGE, ktn)                                                \
    {                                                                        \
        const int buf_ = (BUF); const int nb_ = buf_ ^ 1;                    \
        /* phase 0: B-frags (whole tile) + A quad 0; stage B0,B1 of next */  \
        READ_B(buf_)                                                         \
        LOAD_A(buf_, 0)                                                      \
        if (STAGE) { ST_B(nb_, 0, ktn); ST_B(nb_, 1, ktn); }                 \
        __builtin_amdgcn_s_barrier();                                        \
        MFMA_Q(0)                                                            \
        __builtin_amdgcn_s_barrier();                                        \
        /* phase 1 */                                                        \
        LOAD_A(buf_, 1)                                                      \
        if (STAGE) { ST_B(nb_, 2, ktn); ST_B(nb_, 3, ktn); }                 \
        __builtin_amdgcn_s_barrier();                                        \
        MFMA_Q(1)                                                            \
        if (STAGE) { asm volatile("s_waitcnt vmcnt(4)" ::: "memory"); }      \
        else       { asm volatile("s_waitcnt vmcnt(0)" ::: "memory"); }      \
        __builtin_amdgcn_s_barrier();                                        \
        /* phase 2 */                                                        \
        LOAD_A(buf_, 2)                                                      \
        if (STAGE) { ST_A(nb_, 0, ktn); ST_A(nb_, 2, ktn); }                 \
        __builtin_amdgcn_s_barrier();                                        \
        MFMA_Q(2)                                                            \
        __builtin_amdgcn_s_barrier();                                        \
        /* phase 3 */                                                        \
        LOAD_A(buf_, 3)                                                      \
        if (STAGE) { ST_A(nb_, 1, ktn); ST_A(nb_, 3, ktn); }                 \
        __builtin_amdgcn_s_barrier();                                        \
        MFMA_Q(3)                                                            \
        if (STAGE) { asm volatile("s_waitcnt vmcnt(2)" ::: "memory"); }      \
        __builtin_amdgcn_s_barrier();                                        \
    }

    const int NT = Kd >> 6;
    for (int k = 0; k < NT - 1; ++k) {
        TILE(k & 1, true, (k + 1) << 6);
    }
    TILE((NT - 1) & 1, false, 0);

#undef TILE
#undef MFMA_Q
#undef LOAD_A
#undef READ_B
#undef ST_A
#undef ST_B

    // ---- epilogue ----  C/D: col = lane&15 (lr), row = lkg*4 + reg
    const int r0 = lkg * 4;
    const size_t coff = (size_t)bz * (size_t)batchC;
#pragma unroll
    for (int ri = 0; ri < 8; ++ri) {
#pragma unroll
        for (int j = 0; j < 4; ++j) {
            if (EPI == 4) {
                if (qpath) {
                    const int gcol = bn + wc * 64 + j * 16 + lr;
                    const float bv = b0[gcol];
#pragma unroll
                    for (int r = 0; r < 4; ++r) {
                        const int grow = bm + wr * 128 + ri * 16 + r0 + r;
                        ((unsigned short*)C0)[(size_t)grow * 1024 + gcol] =
                            f2bf((acc[ri][j][r] + bv) * 0.03125f);
                    }
                } else {
                    const int gcol3 = bn + wc * 64 + j * 16 + lr;
                    const int which = gcol3 >> 10;        // block-uniform: 0=K,1=V
                    const int col   = gcol3 & 1023;
                    const float bv  = (which == 0) ? b1[col] : b2[col];
                    if (which == 0) {
                        unsigned short* dst = (unsigned short*)C1 + (size_t)bz * (2048 * 1024);
#pragma unroll
                        for (int r = 0; r < 4; ++r) {
                            const int grow = bm + wr * 128 + ri * 16 + r0 + r;
                            dst[(size_t)grow * 1024 + col] = f2bf(acc[ri][j][r] + bv);
                        }
                    } else {
                        const int m0 = bm + wr * 128 + ri * 16 + r0;
                        ushort4 wv;
                        wv.x = f2bf(acc[ri][j][0] + bv);
                        wv.y = f2bf(acc[ri][j][1] + bv);
                        wv.z = f2bf(acc[ri][j][2] + bv);
                        wv.w = f2bf(acc[ri][j][3] + bv);
                        *(ushort4*)((unsigned short*)C2 + (size_t)bz * (1024 * 2048)
                                    + (size_t)col * 2048 + m0) = wv;
                    }
                }
            } else if (EPI == 1) {
                const int gcol = bn + wc * 64 + j * 16 + lr;
#pragma unroll
                for (int r = 0; r < 4; ++r) {
                    const int grow = bm + wr * 128 + ri * 16 + r0 + r;
                    ((__half*)C0)[coff + (size_t)grow * ldc + gcol] =
                        __float2half(acc[ri][j][r]);
                }
            } else {
                const int gcol = bn + wc * 64 + j * 16 + lr;
#pragma unroll
                for (int r = 0; r < 4; ++r) {
                    const int grow = bm + wr * 128 + ri * 16 + r0 + r;
                    ((float*)C0)[coff + (size_t)grow * ldc + gcol] = acc[ri][j][r];
                }
            }
        }
    }
}

// fp32 -> bf16 conversion, 4 elems/thread
__global__ __launch_bounds__(256)
void conv_f32_bf16(const float4* __restrict__ src, ushort4* __restrict__ dst, int n4)
{
    const int i = blockIdx.x * 256 + threadIdx.x;
    if (i < n4) {
        const float4 v = src[i];
        ushort4 wv;
        wv.x = f2bf(v.x); wv.y = f2bf(v.y); wv.z = f2bf(v.z); wv.w = f2bf(v.w);
        dst[i] = wv;
    }
}

// Per-batch stable compaction of unmasked key positions.
// cidx[b][j] = s-index of j-th unmasked key; pads (nc..ncp) -> 0.
// ncinfo[b] = nc, ncinfo[8+b] = ncp (nc rounded up to 256, min 256).
__global__ __launch_bounds__(256)
void compact_mask(const int* __restrict__ mask, int* __restrict__ cidx,
                  int* __restrict__ ncinfo)
{
    const int b = blockIdx.x;
    const int t = threadIdx.x;
    const int* mb = mask + b * 2048;
    int loc[8];
    int c = 0;
#pragma unroll
    for (int j = 0; j < 8; ++j) {
        const int s = t * 8 + j;
        if (mb[s] != 0) loc[c++] = s;
    }
    __shared__ int ps[256];
    ps[t] = c;
    __syncthreads();
    for (int off = 1; off < 256; off <<= 1) {
        const int v = (t >= off) ? ps[t - off] : 0;
        __syncthreads();
        ps[t] += v;
        __syncthreads();
    }
    const int base = ps[t] - c;
    int* cb = cidx + b * 2048;
    for (int i = 0; i < c; ++i) cb[base + i] = loc[i];
    __syncthreads();
    const int nc  = ps[255];
    int ncp = (nc + 255) & ~255;
    if (ncp < 256) ncp = 256;
    for (int i = nc + t; i < ncp; i += 256) cb[i] = 0;
    if (t == 0) { ncinfo[b] = nc; ncinfo[8 + b] = ncp; }
}

// Row softmax over compacted scores, IN-PLACE: fp16 scores in (cols < nc
// valid), bf16 P out to the SAME buffer (cols < ncp; pads [nc,ncp) get 0).
// Each thread reads and rewrites only its own 8 columns -> race-free.
__global__ __launch_bounds__(256)
void softmax_rows(unsigned short* __restrict__ SP, const int* __restrict__ ncinfo)
{
    const size_t row = blockIdx.x;          // b*2048 + q
    const int b   = (int)(row >> 11);
    const int nc  = ncinfo[b];
    const int ncp = ncinfo[8 + b];
    unsigned short* sp = SP + row * 2048;
    const int t  = threadIdx.x;
    const int c0 = t * 8;
    const bool act = c0 < ncp;

    float s[8];
#pragma unroll
    for (int j = 0; j < 8; ++j) s[j] = NEG_INF;
    if (act) {
        const ushort4 h0 = *(const ushort4*)&sp[c0];
        const ushort4 h1 = *(const ushort4*)&sp[c0 + 4];
        const unsigned short hv[8] = {h0.x, h0.y, h0.z, h0.w, h1.x, h1.y, h1.z, h1.w};
#pragma unroll
        for (int j = 0; j < 8; ++j)
            if (c0 + j < nc) s[j] = h2f(hv[j]);
    }

    float m = fmaxf(fmaxf(fmaxf(s[0], s[1]), fmaxf(s[2], s[3])),
                    fmaxf(fmaxf(s[4], s[5]), fmaxf(s[6], s[7])));

    __shared__ float red[256];
    red[t] = m;
    __syncthreads();
    for (int sw = 128; sw > 0; sw >>= 1) {
        if (t < sw) red[t] = fmaxf(red[t], red[t + sw]);
        __syncthreads();
    }
    const float mx = red[0];
    __syncthreads();

    float e[8];
#pragma unroll
    for (int j = 0; j < 8; ++j) e[j] = __expf(s[j] - mx);
    float s8 = ((e[0] + e[1]) + (e[2] + e[3])) + ((e[4] + e[5]) + (e[6] + e[7]));

    red[t] = s8;
    __syncthreads();
    for (int sw = 128; sw > 0; sw >>= 1) {
        if (t < sw) red[t] += red[t + sw];
        __syncthreads();
    }
    const float inv = 1.0f / red[0];

    if (act) {
        ushort4 w0, w1;
        w0.x = f2bf(e[0] * inv); w0.y = f2bf(e[1] * inv);
        w0.z = f2bf(e[2] * inv); w0.w = f2bf(e[3] * inv);
        w1.x = f2bf(e[4] * inv); w1.y = f2bf(e[5] * inv);
        w1.z = f2bf(e[6] * inv); w1.w = f2bf(e[7] * inv);
        *(ushort4*)&sp[c0]     = w0;
        *(ushort4*)&sp[c0 + 4] = w1;
    }
}

extern "C" void kernel_launch(void* const* d_in, const int* in_sizes, int n_in,
                              void* d_out, int out_size, void* d_ws, size_t ws_size,
                              hipStream_t stream)
{
    const float* x    = (const float*)d_in[0];
    const int*   mask = (const int*)d_in[1];
    const float* Wq   = (const float*)d_in[2];
    const float* bq   = (const float*)d_in[3];
    const float* Wk   = (const float*)d_in[4];
    const float* bk   = (const float*)d_in[5];
    const float* Wv   = (const float*)d_in[6];
    const float* bv   = (const float*)d_in[7];
    float* out = (float*)d_out;

    // Workspace layout (max 199 MiB + 64 B; NO overlaps among live ranges):
    //   [0,32)    Q       [16384][1024] bf16 (pre-scaled 1/32)
    //   [32,64)   Kc      [8][2048][1024] bf16 compacted keys (rows < ncp valid)
    //   [64,96)   Vtc     [8][1024][2048] bf16 compacted V^T (cols < ncp valid)
    //   [96,160)  Sf/P    [8][2048][2048] fp16 scores -> bf16 probs IN-PLACE
    //   [160,192) xb      bf16 x (dead after projections)
    //   [192,198) wb      bf16 weights [3072][1024]
    //   [198,199) cidx    [8][2048] int
    //   [199,..)  ncinfo  [16] int
    char* ws = (char*)d_ws;
    unsigned short* Q   = (unsigned short*)(ws);
    unsigned short* Kc  = (unsigned short*)(ws + (32ull << 20));
    unsigned short* Vtc = (unsigned short*)(ws + (64ull << 20));
    unsigned short* SP  = (unsigned short*)(ws + (96ull << 20));
    unsigned short* xb  = (unsigned short*)(ws + (160ull << 20));
    unsigned short* wb  = (unsigned short*)(ws + (192ull << 20));
    int*            cidx   = (int*)(ws + (198ull << 20));
    int*            ncinfo = (int*)(ws + (199ull << 20));

    const int D = 1024, S = 2048, B = 8, Mtot = 16384;
    dim3 blk2(256), blk5(512);

    // ---- fp32 -> bf16 conversions (weights stacked -> [3072][1024]) ----
    conv_f32_bf16<<<dim3((Mtot * D / 4) / 256), blk2, 0, stream>>>((const float4*)x, (ushort4*)xb, Mtot * D / 4);
    conv_f32_bf16<<<dim3((D * D / 4) / 256), blk2, 0, stream>>>((const float4*)Wq, (ushort4*)(wb + 0ull * D * D), D * D / 4);
    conv_f32_bf16<<<dim3((D * D / 4) / 256), blk2, 0, stream>>>((const float4*)Wk, (ushort4*)(wb + 1ull * D * D), D * D / 4);
    conv_f32_bf16<<<dim3((D * D / 4) / 256), blk2, 0, stream>>>((const float4*)Wv, (ushort4*)(wb + 2ull * D * D), D * D / 4);

    // ---- mask compaction ----
    compact_mask<<<dim3(B), blk2, 0, stream>>>(mask, cidx, ncinfo);

    // ---- merged projections: Q (256 tiles) + KV gathered (512 tiles, early-exit) ----
    gemm256<4><<<dim3(768), blk5, 0, stream>>>(
        xb, wb, Q, Kc, Vtc, bq, bk, bv, cidx, ncinfo,
        D, 1024, 1024, 1024, 0, 0, 0, 0, 0);

    // ---- scores: S_b = Q_b @ Kc_b^T (scale folded into Q), fp16 out ----
    gemm256<1><<<dim3(512), blk5, 0, stream>>>(
        Q, Kc, SP, nullptr, nullptr, nullptr, nullptr, nullptr, nullptr, ncinfo,
        D, 1024, 1024, 2048, (long)S * D, (long)S * D, (long)S * S, 8, 8);

    // ---- softmax over compacted cols, in-place (bf16 P out, pads = 0) ----
    softmax_rows<<<dim3(B * S), blk2, 0, stream>>>(SP, ncinfo);

    // ---- out: O_b = P_b @ Vc_b = P_b . Vtc_b^T (runtime K = ncp_b) ----
    gemm256<2><<<dim3(256), blk5, 0, stream>>>(
        SP, Vtc, out, nullptr, nullptr, nullptr, nullptr, nullptr, nullptr, ncinfo,
        S, 2048, 2048, 1024, (long)S * 2048, (long)D * S, (long)S * D, 8, 4);
}

// Round 10
// 250.104 us; speedup vs baseline: 1.0779x; 1.0779x over previous
//
#include <hip/hip_runtime.h>
#include <hip/hip_bf16.h>
#include <hip/hip_fp16.h>

#define NEG_INF -1000000000.0f

typedef __attribute__((ext_vector_type(8))) short bf16x8;
typedef __attribute__((ext_vector_type(4))) float f32x4;

__device__ __forceinline__ unsigned short f2bf(float f) {
    unsigned int u = __float_as_uint(f);
    u += 0x7FFFu + ((u >> 16) & 1u);
    return (unsigned short)(u >> 16);
}

__device__ __forceinline__ float h2f(unsigned short us) {
    __half h;
    __builtin_memcpy(&h, &us, 2);
    return __half2float(h);
}

#define GLOAD_LDS16(gp, lp)                                                  \
    __builtin_amdgcn_global_load_lds(                                        \
        (const __attribute__((address_space(1))) void*)(gp),                 \
        (__attribute__((address_space(3))) void*)(lp), 16, 0, 0)

// 256x256-tile BT-form bf16 GEMM (m201-style 4-phase, T1/T2/T5, counted vmcnt).
// EPI: 4 = proj-main: bid<256 -> Q tile; else KV tile over compact rows [0,1024)
//      1 = scores-main (fp16 out, cols [0,1024))
//      2 = PV (fp32 out; runtime K = ncp[bz])
template<int EPI>
__global__ __launch_bounds__(512, 2)
void gemm256(const unsigned short* __restrict__ A, const unsigned short* __restrict__ B,
             void* __restrict__ C0, void* __restrict__ C1, void* __restrict__ C2,
             const float* __restrict__ b0, const float* __restrict__ b1,
             const float* __restrict__ b2,
             const int* __restrict__ cidx, const int* __restrict__ ncinfo,
             int K, long lda, long ldb, long ldc,
             long batchA, long batchB, long batchC,
             int gx, int gy)
{
    __shared__ unsigned short As[2][16384];
    __shared__ unsigned short Bs[2][16384];

    // T1: bijective XCD swizzle (all grids % 8 == 0)
    int bid = blockIdx.x;
    bid = (bid & 7) * ((int)gridDim.x >> 3) + (bid >> 3);

    int bz = 0, bm, bn;
    bool qpath = false;
    if (EPI == 4) {
        if (bid < 256) {                    // Q projection tile
            qpath = true;
            bm = (bid >> 2) * 256;          // over 16384 rows
            bn = (bid & 3) * 256;           // over 1024 cols
        } else {                            // KV tile, compact rows [0,1024)
            const int kid = bid - 256;
            bz = kid >> 5;
            const int r2 = kid & 31;
            bm = (r2 >> 3) * 256;           // 0,256,512,768
            bn = (r2 & 7) * 256;            // 0..2047: K | V
            if (bm >= ncinfo[8 + bz]) return;
        }
    } else if (EPI == 1) {
        bz = bid >> 5;
        const int r = bid & 31;
        bm = (r >> 2) * 256;                // 8 M-tiles over 2048 q-rows
        bn = (r & 3) * 256;                 // cols [0,1024)
        if (bn >= ncinfo[8 + bz]) return;
    } else {
        const int gxy = gx * gy;
        bz = bid / gxy;
        const int rem = bid - bz * gxy;
        const int tm = rem / gy;
        bm = tm * 256;
        bn = (rem - tm * gy) * 256;
    }

    const int t    = threadIdx.x;
    const int lane = t & 63;
    const int w    = t >> 6;
    const int wr   = w >> 2;
    const int wc   = w & 3;
    const int lr   = lane & 15;
    const int lkg  = lane >> 4;
    const int sx8  = (lr & 7) * 8;
    const int e0   = (lkg * 8) ^ sx8;

    const int tr  = t >> 3;
    const int tcs = ((t & 7) ^ (tr & 7)) * 8;
    const int wb512 = w * 512;

    const unsigned short* ApG[4];
    const unsigned short* Bb;
    if (EPI == 4) {
        if (qpath) {
#pragma unroll
            for (int L = 0; L < 4; ++L)
                ApG[L] = A + (size_t)(bm + L * 64 + tr) * lda + tcs;
            Bb = B + (size_t)(bn + tr) * ldb + tcs;            // Wq rows
        } else {
#pragma unroll
            for (int L = 0; L < 4; ++L) {
                const int rr = cidx[bz * 2048 + bm + L * 64 + tr];
                ApG[L] = A + ((size_t)bz * 2048 + rr) * lda + tcs;
            }
            Bb = B + (size_t)(1024 + bn + tr) * ldb + tcs;     // Wk|Wv rows
        }
    } else {
        const unsigned short* Ab = A + (size_t)bz * (size_t)batchA
                                     + (size_t)(bm + tr) * lda + tcs;
#pragma unroll
        for (int L = 0; L < 4; ++L) ApG[L] = Ab + (size_t)L * 64 * lda;
        Bb = B + (size_t)bz * (size_t)batchB + (size_t)(bn + tr) * ldb + tcs;
    }

    const int Kd = (EPI == 2) ? ncinfo[8 + bz] : K;

#define ST_A(nb, L, kt) GLOAD_LDS16(ApG[L] + (kt), &As[nb][(L) * 4096 + wb512])
#define ST_B(nb, L, kt) GLOAD_LDS16(Bb + (size_t)(L) * 64 * ldb + (kt), &Bs[nb][(L) * 4096 + wb512])

    f32x4 acc[8][4];
#pragma unroll
    for (int i = 0; i < 8; ++i)
#pragma unroll
        for (int j = 0; j < 4; ++j)
            acc[i][j] = f32x4{0.f, 0.f, 0.f, 0.f};

    ST_B(0, 0, 0); ST_B(0, 1, 0); ST_B(0, 2, 0); ST_B(0, 3, 0);
    ST_A(0, 0, 0); ST_A(0, 2, 0); ST_A(0, 1, 0); ST_A(0, 3, 0);
    asm volatile("s_waitcnt vmcnt(2)" ::: "memory");
    __builtin_amdgcn_s_barrier();

    bf16x8 a[2][2], b[4][2];

#define READ_B(BUF)                                                          \
    _Pragma("unroll") for (int j = 0; j < 4; ++j) {                          \
        const int Rb = wc * 64 + j * 16 + lr;                                \
        b[j][0] = *(const bf16x8*)&Bs[BUF][Rb * 64 + e0];                    \
        b[j][1] = *(const bf16x8*)&Bs[BUF][Rb * 64 + (e0 ^ 32)];             \
    }

#define LOAD_A(BUF, qp)                                                      \
    _Pragma("unroll") for (int i2 = 0; i2 < 2; ++i2) {                       \
        const int Ra = wr * 128 + (qp) * 32 + i2 * 16 + lr;                  \
        a[i2][0] = *(const bf16x8*)&As[BUF][Ra * 64 + e0];                   \
        a[i2][1] = *(const bf16x8*)&As[BUF][Ra * 64 + (e0 ^ 32)];            \
    }

#define MFMA_Q(qp)                                                           \
    __builtin_amdgcn_s_setprio(1);                                           \
    _Pragma("unroll") for (int kk = 0; kk < 2; ++kk)                         \
    _Pragma("unroll") for (int i2 = 0; i2 < 2; ++i2)                         \
    _Pragma("unroll") for (int j = 0; j < 4; ++j)                            \
        acc[(qp) * 2 + i2][j] = __builtin_amdgcn_mfma_f32_16x16x32_bf16(     \
            a[i2][kk], b[j][kk], acc[(qp) * 2 + i2][j], 0, 0, 0);            \
    __builtin_amdgcn_s_setprio(0);

#define TILE(BUF, STAGE, ktn)                                                \
    {                                                                        \
        const int buf_ = (BUF); const int nb_ = buf_ ^ 1;                    \
        READ_B(buf_)                                                         \
        LOAD_A(buf_, 0)                                                      \
        if (STAGE) { ST_B(nb_, 0, ktn); ST_B(nb_, 1, ktn); }                 \
        __builtin_amdgcn_s_barrier();                                        \
        MFMA_Q(0)                                                            \
        __builtin_amdgcn_s_barrier();                                        \
        LOAD_A(buf_, 1)                                                      \
        if (STAGE) { ST_B(nb_, 2, ktn); ST_B(nb_, 3, ktn); }                 \
        __builtin_amdgcn_s_barrier();                                        \
        MFMA_Q(1)                                                            \
        if (STAGE) { asm volatile("s_waitcnt vmcnt(4)" ::: "memory"); }      \
        else       { asm volatile("s_waitcnt vmcnt(0)" ::: "memory"); }      \
        __builtin_amdgcn_s_barrier();                                        \
        LOAD_A(buf_, 2)                                                      \
        if (STAGE) { ST_A(nb_, 0, ktn); ST_A(nb_, 2, ktn); }                 \
        __builtin_amdgcn_s_barrier();                                        \
        MFMA_Q(2)                                                            \
        __builtin_amdgcn_s_barrier();                                        \
        LOAD_A(buf_, 3)                                                      \
        if (STAGE) { ST_A(nb_, 1, ktn); ST_A(nb_, 3, ktn); }                 \
        __builtin_amdgcn_s_barrier();                                        \
        MFMA_Q(3)                                                            \
        if (STAGE) { asm volatile("s_waitcnt vmcnt(2)" ::: "memory"); }      \
        __builtin_amdgcn_s_barrier();                                        \
    }

    const int NT = Kd >> 6;
    for (int k = 0; k < NT - 1; ++k) {
        TILE(k & 1, true, (k + 1) << 6);
    }
    TILE((NT - 1) & 1, false, 0);

#undef TILE
#undef MFMA_Q
#undef LOAD_A
#undef READ_B
#undef ST_A
#undef ST_B

    const int r0 = lkg * 4;
    const size_t coff = (size_t)bz * (size_t)batchC;
#pragma unroll
    for (int ri = 0; ri < 8; ++ri) {
#pragma unroll
        for (int j = 0; j < 4; ++j) {
            if (EPI == 4) {
                if (qpath) {
                    const int gcol = bn + wc * 64 + j * 16 + lr;
                    const float bv = b0[gcol];
#pragma unroll
                    for (int r = 0; r < 4; ++r) {
                        const int grow = bm + wr * 128 + ri * 16 + r0 + r;
                        ((unsigned short*)C0)[(size_t)grow * 1024 + gcol] =
                            f2bf((acc[ri][j][r] + bv) * 0.03125f);
                    }
                } else {
                    const int gcol3 = bn + wc * 64 + j * 16 + lr;
                    const int which = gcol3 >> 10;
                    const int col   = gcol3 & 1023;
                    const float bv  = (which == 0) ? b1[col] : b2[col];
                    if (which == 0) {
                        unsigned short* dst = (unsigned short*)C1 + (size_t)bz * (2048 * 1024);
#pragma unroll
                        for (int r = 0; r < 4; ++r) {
                            const int grow = bm + wr * 128 + ri * 16 + r0 + r;
                            dst[(size_t)grow * 1024 + col] = f2bf(acc[ri][j][r] + bv);
                        }
                    } else {
                        const int m0 = bm + wr * 128 + ri * 16 + r0;
                        ushort4 wv;
                        wv.x = f2bf(acc[ri][j][0] + bv);
                        wv.y = f2bf(acc[ri][j][1] + bv);
                        wv.z = f2bf(acc[ri][j][2] + bv);
                        wv.w = f2bf(acc[ri][j][3] + bv);
                        *(ushort4*)((unsigned short*)C2 + (size_t)bz * (1024 * 2048)
                                    + (size_t)col * 2048 + m0) = wv;
                    }
                }
            } else if (EPI == 1) {
                const int gcol = bn + wc * 64 + j * 16 + lr;
#pragma unroll
                for (int r = 0; r < 4; ++r) {
                    const int grow = bm + wr * 128 + ri * 16 + r0 + r;
                    ((__half*)C0)[(size_t)bz * (2048 * 2048) + (size_t)grow * 2048 + gcol] =
                        __float2half(acc[ri][j][r]);
                }
            } else {
                const int gcol = bn + wc * 64 + j * 16 + lr;
#pragma unroll
                for (int r = 0; r < 4; ++r) {
                    const int grow = bm + wr * 128 + ri * 16 + r0 + r;
                    ((float*)C0)[coff + (size_t)grow * ldc + gcol] = acc[ri][j][r];
                }
            }
        }
    }
}

// 128x128-tile tail GEMM (m97-style single-buffer, 4 waves, T2 pre-swizzle).
// TEPI 0: KV-proj tail (gathered compact rows [1024,ncp), N=2048 K|V)
// TEPI 1: scores tail (cols [1024,ncp), fp16 out)
template<int TEPI>
__global__ __launch_bounds__(256)
void gemm_tail(const unsigned short* __restrict__ A, const unsigned short* __restrict__ B,
               void* __restrict__ C0, void* __restrict__ C1,
               const float* __restrict__ b0, const float* __restrict__ b1,
               const int* __restrict__ cidx, const int* __restrict__ ncinfo)
{
    __shared__ unsigned short As[128 * 64];
    __shared__ unsigned short Bs[128 * 64];

    int bid = blockIdx.x;
    bid = (bid & 7) * 32 + (bid >> 3);      // grid 256
    const int bz = bid >> 5;
    const int r  = bid & 31;
    int bm, bn;
    if (TEPI == 0) {
        bm = 1024 + (r >> 4) * 128;         // compact rows
        bn = (r & 15) * 128;                // 0..2047: K | V
        if (bm >= ncinfo[8 + bz]) return;
    } else {
        bm = (r >> 1) * 128;                // q rows (batch-local)
        bn = 1024 + (r & 1) * 128;          // score cols
        if (bn >= ncinfo[8 + bz]) return;
    }

    const int t    = threadIdx.x;
    const int lane = t & 63;
    const int w    = t >> 6;
    const int wm   = (w >> 1) * 64;
    const int wn   = (w & 1) * 64;
    const int lr   = lane & 15;
    const int lk8  = (lane >> 4) * 8;
    const int e0   = lk8 ^ ((lr & 7) * 8);  // T2 read-side

    // staging: pass p, wave w -> rows p*32 + w*8 + (lane>>3); swizzled src col
    const int srow = w * 8 + (lane >> 3);
    const int scol = (((lane & 7) ^ (srow & 7))) * 8;

    const unsigned short* Arow[4];
    const unsigned short* Brow[4];
#pragma unroll
    for (int p = 0; p < 4; ++p) {
        const int ra = bm + p * 32 + srow;
        const int rb = bn + p * 32 + srow;
        if (TEPI == 0) {
            const int rr = cidx[bz * 2048 + ra];
            Arow[p] = A + ((size_t)bz * 2048 + rr) * 1024 + scol;
            Brow[p] = B + (size_t)rb * 1024 + scol;              // Wk|Wv rows
        } else {
            Arow[p] = A + (size_t)bz * (2048 * 1024) + (size_t)ra * 1024 + scol;
            Brow[p] = B + (size_t)bz * (2048 * 1024) + (size_t)rb * 1024 + scol;
        }
    }

    f32x4 acc[4][4];
#pragma unroll
    for (int i = 0; i < 4; ++i)
#pragma unroll
        for (int j = 0; j < 4; ++j)
            acc[i][j] = f32x4{0.f, 0.f, 0.f, 0.f};

    for (int kt = 0; kt < 1024; kt += 64) {
#pragma unroll
        for (int p = 0; p < 4; ++p) {
            GLOAD_LDS16(Arow[p] + kt, &As[(p * 32 + w * 8) * 64]);
            GLOAD_LDS16(Brow[p] + kt, &Bs[(p * 32 + w * 8) * 64]);
        }
        asm volatile("s_waitcnt vmcnt(0)" ::: "memory");
        __builtin_amdgcn_s_barrier();

#pragma unroll
        for (int kk = 0; kk < 2; ++kk) {
            bf16x8 af[4], bfr[4];
#pragma unroll
            for (int i = 0; i < 4; ++i) {
                const int Ra = wm + i * 16 + lr;
                af[i] = *(const bf16x8*)&As[Ra * 64 + (kk ? (e0 ^ 32) : e0)];
            }
#pragma unroll
            for (int j = 0; j < 4; ++j) {
                const int Rb = wn + j * 16 + lr;
                bfr[j] = *(const bf16x8*)&Bs[Rb * 64 + (kk ? (e0 ^ 32) : e0)];
            }
#pragma unroll
            for (int i = 0; i < 4; ++i)
#pragma unroll
                for (int j = 0; j < 4; ++j)
                    acc[i][j] = __builtin_amdgcn_mfma_f32_16x16x32_bf16(af[i], bfr[j], acc[i][j], 0, 0, 0);
        }
        __builtin_amdgcn_s_barrier();
    }

    const int r0 = (lane >> 4) * 4;
#pragma unroll
    for (int i = 0; i < 4; ++i) {
#pragma unroll
        for (int j = 0; j < 4; ++j) {
            if (TEPI == 0) {
                const int gcol3 = bn + wn + j * 16 + lr;
                const int which = gcol3 >> 10;
                const int col   = gcol3 & 1023;
                const float bv  = (which == 0) ? b0[col] : b1[col];
                if (which == 0) {
                    unsigned short* dst = (unsigned short*)C0 + (size_t)bz * (2048 * 1024);
#pragma unroll
                    for (int rr = 0; rr < 4; ++rr) {
                        const int grow = bm + wm + i * 16 + r0 + rr;
                        dst[(size_t)grow * 1024 + col] = f2bf(acc[i][j][rr] + bv);
                    }
                } else {
                    const int m0 = bm + wm + i * 16 + r0;
                    ushort4 wv;
                    wv.x = f2bf(acc[i][j][0] + bv);
                    wv.y = f2bf(acc[i][j][1] + bv);
                    wv.z = f2bf(acc[i][j][2] + bv);
                    wv.w = f2bf(acc[i][j][3] + bv);
                    *(ushort4*)((unsigned short*)C1 + (size_t)bz * (1024 * 2048)
                                + (size_t)col * 2048 + m0) = wv;
                }
            } else {
                const int gcol = bn + wn + j * 16 + lr;
#pragma unroll
                for (int rr = 0; rr < 4; ++rr) {
                    const int grow = bm + wm + i * 16 + r0 + rr;
                    ((__half*)C0)[(size_t)bz * (2048 * 2048) + (size_t)grow * 2048 + gcol] =
                        __float2half(acc[i][j][rr]);
                }
            }
        }
    }
}

// Fused prep: x->bf16 (16384 blocks), Wq/Wk/Wv->bf16 (3x1024), compact (8).
__global__ __launch_bounds__(256)
void prep(const float4* __restrict__ x, const float4* __restrict__ Wq,
          const float4* __restrict__ Wk, const float4* __restrict__ Wv,
          ushort4* __restrict__ xb, ushort4* __restrict__ wb,
          const int* __restrict__ mask, int* __restrict__ cidx,
          int* __restrict__ ncinfo)
{
    const int bidx = blockIdx.x;
    const int t = threadIdx.x;
    if (bidx < 19456) {
        const float4* src;
        ushort4* dst;
        int i;
        if (bidx < 16384)       { src = x;  dst = xb;               i = bidx * 256 + t; }
        else if (bidx < 17408)  { src = Wq; dst = wb;               i = (bidx - 16384) * 256 + t; }
        else if (bidx < 18432)  { src = Wk; dst = wb + 262144;      i = (bidx - 17408) * 256 + t; }
        else                    { src = Wv; dst = wb + 524288;      i = (bidx - 18432) * 256 + t; }
        const float4 v = src[i];
        ushort4 wv;
        wv.x = f2bf(v.x); wv.y = f2bf(v.y); wv.z = f2bf(v.z); wv.w = f2bf(v.w);
        dst[i] = wv;
        return;
    }
    // compact for batch b
    const int b = bidx - 19456;
    const int* mb = mask + b * 2048;
    int loc[8];
    int c = 0;
#pragma unroll
    for (int j = 0; j < 8; ++j) {
        const int s = t * 8 + j;
        if (mb[s] != 0) loc[c++] = s;
    }
    __shared__ int ps[256];
    ps[t] = c;
    __syncthreads();
    for (int off = 1; off < 256; off <<= 1) {
        const int v = (t >= off) ? ps[t - off] : 0;
        __syncthreads();
        ps[t] += v;
        __syncthreads();
    }
    const int base = ps[t] - c;
    int* cb = cidx + b * 2048;
    for (int i = 0; i < c; ++i) cb[base + i] = loc[i];
    __syncthreads();
    const int nc  = ps[255];
    int ncp = (nc + 255) & ~255;
    if (ncp < 256) ncp = 256;
    for (int i = nc + t; i < ncp; i += 256) cb[i] = 0;
    if (t == 0) { ncinfo[b] = nc; ncinfo[8 + b] = ncp; }
}

// Row softmax over compacted scores, IN-PLACE (fp16 in -> bf16 P out).
__global__ __launch_bounds__(256)
void softmax_rows(unsigned short* __restrict__ SP, const int* __restrict__ ncinfo)
{
    const size_t row = blockIdx.x;
    const int b   = (int)(row >> 11);
    const int nc  = ncinfo[b];
    const int ncp = ncinfo[8 + b];
    unsigned short* sp = SP + row * 2048;
    const int t  = threadIdx.x;
    const int c0 = t * 8;
    const bool act = c0 < ncp;

    float s[8];
#pragma unroll
    for (int j = 0; j < 8; ++j) s[j] = NEG_INF;
    if (act) {
        const ushort4 h0 = *(const ushort4*)&sp[c0];
        const ushort4 h1 = *(const ushort4*)&sp[c0 + 4];
        const unsigned short hv[8] = {h0.x, h0.y, h0.z, h0.w, h1.x, h1.y, h1.z, h1.w};
#pragma unroll
        for (int j = 0; j < 8; ++j)
            if (c0 + j < nc) s[j] = h2f(hv[j]);
    }

    float m = fmaxf(fmaxf(fmaxf(s[0], s[1]), fmaxf(s[2], s[3])),
                    fmaxf(fmaxf(s[4], s[5]), fmaxf(s[6], s[7])));

    __shared__ float red[256];
    red[t] = m;
    __syncthreads();
    for (int sw = 128; sw > 0; sw >>= 1) {
        if (t < sw) red[t] = fmaxf(red[t], red[t + sw]);
        __syncthreads();
    }
    const float mx = red[0];
    __syncthreads();

    float e[8];
#pragma unroll
    for (int j = 0; j < 8; ++j) e[j] = __expf(s[j] - mx);
    float s8 = ((e[0] + e[1]) + (e[2] + e[3])) + ((e[4] + e[5]) + (e[6] + e[7]));

    red[t] = s8;
    __syncthreads();
    for (int sw = 128; sw > 0; sw >>= 1) {
        if (t < sw) red[t] += red[t + sw];
        __syncthreads();
    }
    const float inv = 1.0f / red[0];

    if (act) {
        ushort4 w0, w1;
        w0.x = f2bf(e[0] * inv); w0.y = f2bf(e[1] * inv);
        w0.z = f2bf(e[2] * inv); w0.w = f2bf(e[3] * inv);
        w1.x = f2bf(e[4] * inv); w1.y = f2bf(e[5] * inv);
        w1.z = f2bf(e[6] * inv); w1.w = f2bf(e[7] * inv);
        *(ushort4*)&sp[c0]     = w0;
        *(ushort4*)&sp[c0 + 4] = w1;
    }
}

extern "C" void kernel_launch(void* const* d_in, const int* in_sizes, int n_in,
                              void* d_out, int out_size, void* d_ws, size_t ws_size,
                              hipStream_t stream)
{
    const float* x    = (const float*)d_in[0];
    const int*   mask = (const int*)d_in[1];
    const float* Wq   = (const float*)d_in[2];
    const float* bq   = (const float*)d_in[3];
    const float* Wk   = (const float*)d_in[4];
    const float* bk   = (const float*)d_in[5];
    const float* Wv   = (const float*)d_in[6];
    const float* bv   = (const float*)d_in[7];
    float* out = (float*)d_out;

    // Workspace (no live-range overlaps):
    //   [0,32)    Q   [16384][1024] bf16 (pre-scaled 1/32)
    //   [32,64)   Kc  [8][2048][1024] bf16 compact keys
    //   [64,96)   Vtc [8][1024][2048] bf16 compact V^T
    //   [96,160)  SP  [8][2048][2048] fp16 scores -> bf16 P in-place
    //   [160,192) xb  bf16 x
    //   [192,198) wb  bf16 weights [3072][1024]
    //   [198,199) cidx [8][2048]
    //   [199,..)  ncinfo [16]
    char* ws = (char*)d_ws;
    unsigned short* Q   = (unsigned short*)(ws);
    unsigned short* Kc  = (unsigned short*)(ws + (32ull << 20));
    unsigned short* Vtc = (unsigned short*)(ws + (64ull << 20));
    unsigned short* SP  = (unsigned short*)(ws + (96ull << 20));
    unsigned short* xb  = (unsigned short*)(ws + (160ull << 20));
    unsigned short* wb  = (unsigned short*)(ws + (192ull << 20));
    int*            cidx   = (int*)(ws + (198ull << 20));
    int*            ncinfo = (int*)(ws + (199ull << 20));

    const int D = 1024, S = 2048, B = 8;
    dim3 blk2(256), blk5(512);

    // ---- fused prep: conversions + compaction ----
    prep<<<dim3(19464), blk2, 0, stream>>>(
        (const float4*)x, (const float4*)Wq, (const float4*)Wk, (const float4*)Wv,
        (ushort4*)xb, (ushort4*)wb, mask, cidx, ncinfo);

    // ---- proj-main: Q (256 tiles) + KV compact rows [0,1024) (256 tiles) = 2 rounds ----
    gemm256<4><<<dim3(512), blk5, 0, stream>>>(
        xb, wb, Q, Kc, Vtc, bq, bk, bv, cidx, ncinfo,
        D, 1024, 1024, 1024, 0, 0, 0, 0, 0);

    // ---- proj-tail: KV compact rows [1024, ncp) (128^2 tiles) ----
    gemm_tail<0><<<dim3(256), blk2, 0, stream>>>(
        xb, wb + 1ull * D * D, Kc, Vtc, bk, bv, cidx, ncinfo);

    // ---- scores-main: cols [0,1024) (256 tiles = 1 round), fp16 out ----
    gemm256<1><<<dim3(256), blk5, 0, stream>>>(
        Q, Kc, SP, nullptr, nullptr, nullptr, nullptr, nullptr, cidx, ncinfo,
        D, 1024, 1024, 2048, (long)S * D, (long)S * D, (long)S * S, 0, 0);

    // ---- scores-tail: cols [1024, ncp) ----
    gemm_tail<1><<<dim3(256), blk2, 0, stream>>>(
        Q, Kc, SP, nullptr, nullptr, nullptr, cidx, ncinfo);

    // ---- softmax in-place ----
    softmax_rows<<<dim3(B * S), blk2, 0, stream>>>(SP, ncinfo);

    // ---- PV: O = P . Vtc^T (runtime K = ncp) ----
    gemm256<2><<<dim3(256), blk5, 0, stream>>>(
        SP, Vtc, out, nullptr, nullptr, nullptr, nullptr, nullptr, cidx, ncinfo,
        S, 2048, 2048, 1024, (long)S * 2048, (long)D * S, (long)S * D, 8, 4);
}

// Round 11
// 244.550 us; speedup vs baseline: 1.1023x; 1.0227x over previous
//
#include <hip/hip_runtime.h>
#include <hip/hip_bf16.h>
#include <hip/hip_fp16.h>

#define NEG_INF -1000000000.0f

typedef __attribute__((ext_vector_type(8))) short bf16x8;
typedef __attribute__((ext_vector_type(4))) float f32x4;

__device__ __forceinline__ unsigned short f2bf(float f) {
    unsigned int u = __float_as_uint(f);
    u += 0x7FFFu + ((u >> 16) & 1u);
    return (unsigned short)(u >> 16);
}

__device__ __forceinline__ float h2f(unsigned short us) {
    __half h;
    __builtin_memcpy(&h, &us, 2);
    return __half2float(h);
}

#define GLOAD_LDS16(gp, lp)                                                  \
    __builtin_amdgcn_global_load_lds(                                        \
        (const __attribute__((address_space(1))) void*)(gp),                 \
        (__attribute__((address_space(3))) void*)(lp), 16, 0, 0)

// 256x256-tile BT-form bf16 GEMM (m201-style 4-phase, T1/T2/T5, counted vmcnt).
// EPI: 4 = proj-main: bid<256 -> Q tile; else KV tile over compact rows [0,1024)
//      1 = scores-main (fp16 out, cols [0,1024))
//      2 = PV (fp32 out; runtime K = ncp[bz])
template<int EPI>
__global__ __launch_bounds__(512, 2)
void gemm256(const unsigned short* __restrict__ A, const unsigned short* __restrict__ B,
             void* __restrict__ C0, void* __restrict__ C1, void* __restrict__ C2,
             const float* __restrict__ b0, const float* __restrict__ b1,
             const float* __restrict__ b2,
             const int* __restrict__ cidx, const int* __restrict__ ncinfo,
             int K, long lda, long ldb, long ldc,
             long batchA, long batchB, long batchC,
             int gx, int gy)
{
    __shared__ unsigned short As[2][16384];
    __shared__ unsigned short Bs[2][16384];

    // T1: bijective XCD swizzle (all grids % 8 == 0)
    int bid = blockIdx.x;
    bid = (bid & 7) * ((int)gridDim.x >> 3) + (bid >> 3);

    int bz = 0, bm, bn;
    bool qpath = false;
    if (EPI == 4) {
        if (bid < 256) {                    // Q projection tile
            qpath = true;
            bm = (bid >> 2) * 256;          // over 16384 rows
            bn = (bid & 3) * 256;           // over 1024 cols
        } else {                            // KV tile, compact rows [0,1024)
            const int kid = bid - 256;
            bz = kid >> 5;
            const int r2 = kid & 31;
            bm = (r2 >> 3) * 256;           // 0,256,512,768
            bn = (r2 & 7) * 256;            // 0..2047: K | V
            if (bm >= ncinfo[8 + bz]) return;
        }
    } else if (EPI == 1) {
        bz = bid >> 5;
        const int r = bid & 31;
        bm = (r >> 2) * 256;                // 8 M-tiles over 2048 q-rows
        bn = (r & 3) * 256;                 // cols [0,1024)
        if (bn >= ncinfo[8 + bz]) return;
    } else {
        const int gxy = gx * gy;
        bz = bid / gxy;
        const int rem = bid - bz * gxy;
        const int tm = rem / gy;
        bm = tm * 256;
        bn = (rem - tm * gy) * 256;
    }

    const int t    = threadIdx.x;
    const int lane = t & 63;
    const int w    = t >> 6;
    const int wr   = w >> 2;
    const int wc   = w & 3;
    const int lr   = lane & 15;
    const int lkg  = lane >> 4;
    const int sx8  = (lr & 7) * 8;
    const int e0   = (lkg * 8) ^ sx8;

    const int tr  = t >> 3;
    const int tcs = ((t & 7) ^ (tr & 7)) * 8;
    const int wb512 = w * 512;

    const unsigned short* ApG[4];
    const unsigned short* Bb;
    if (EPI == 4) {
        if (qpath) {
#pragma unroll
            for (int L = 0; L < 4; ++L)
                ApG[L] = A + (size_t)(bm + L * 64 + tr) * lda + tcs;
            Bb = B + (size_t)(bn + tr) * ldb + tcs;            // Wq rows
        } else {
#pragma unroll
            for (int L = 0; L < 4; ++L) {
                const int rr = cidx[bz * 2048 + bm + L * 64 + tr];
                ApG[L] = A + ((size_t)bz * 2048 + rr) * lda + tcs;
            }
            Bb = B + (size_t)(1024 + bn + tr) * ldb + tcs;     // Wk|Wv rows
        }
    } else {
        const unsigned short* Ab = A + (size_t)bz * (size_t)batchA
                                     + (size_t)(bm + tr) * lda + tcs;
#pragma unroll
        for (int L = 0; L < 4; ++L) ApG[L] = Ab + (size_t)L * 64 * lda;
        Bb = B + (size_t)bz * (size_t)batchB + (size_t)(bn + tr) * ldb + tcs;
    }

    const int Kd = (EPI == 2) ? ncinfo[8 + bz] : K;

#define ST_A(nb, L, kt) GLOAD_LDS16(ApG[L] + (kt), &As[nb][(L) * 4096 + wb512])
#define ST_B(nb, L, kt) GLOAD_LDS16(Bb + (size_t)(L) * 64 * ldb + (kt), &Bs[nb][(L) * 4096 + wb512])

    f32x4 acc[8][4];
#pragma unroll
    for (int i = 0; i < 8; ++i)
#pragma unroll
        for (int j = 0; j < 4; ++j)
            acc[i][j] = f32x4{0.f, 0.f, 0.f, 0.f};

    ST_B(0, 0, 0); ST_B(0, 1, 0); ST_B(0, 2, 0); ST_B(0, 3, 0);
    ST_A(0, 0, 0); ST_A(0, 2, 0); ST_A(0, 1, 0); ST_A(0, 3, 0);
    asm volatile("s_waitcnt vmcnt(2)" ::: "memory");
    __builtin_amdgcn_s_barrier();

    bf16x8 a[2][2], b[4][2];

#define READ_B(BUF)                                                          \
    _Pragma("unroll") for (int j = 0; j < 4; ++j) {                          \
        const int Rb = wc * 64 + j * 16 + lr;                                \
        b[j][0] = *(const bf16x8*)&Bs[BUF][Rb * 64 + e0];                    \
        b[j][1] = *(const bf16x8*)&Bs[BUF][Rb * 64 + (e0 ^ 32)];             \
    }

#define LOAD_A(BUF, qp)                                                      \
    _Pragma("unroll") for (int i2 = 0; i2 < 2; ++i2) {                       \
        const int Ra = wr * 128 + (qp) * 32 + i2 * 16 + lr;                  \
        a[i2][0] = *(const bf16x8*)&As[BUF][Ra * 64 + e0];                   \
        a[i2][1] = *(const bf16x8*)&As[BUF][Ra * 64 + (e0 ^ 32)];            \
    }

#define MFMA_Q(qp)                                                           \
    __builtin_amdgcn_s_setprio(1);                                           \
    _Pragma("unroll") for (int kk = 0; kk < 2; ++kk)                         \
    _Pragma("unroll") for (int i2 = 0; i2 < 2; ++i2)                         \
    _Pragma("unroll") for (int j = 0; j < 4; ++j)                            \
        acc[(qp) * 2 + i2][j] = __builtin_amdgcn_mfma_f32_16x16x32_bf16(     \
            a[i2][kk], b[j][kk], acc[(qp) * 2 + i2][j], 0, 0, 0);            \
    __builtin_amdgcn_s_setprio(0);

#define TILE(BUF, STAGE, ktn)                                                \
    {                                                                        \
        const int buf_ = (BUF); const int nb_ = buf_ ^ 1;                    \
        READ_B(buf_)                                                         \
        LOAD_A(buf_, 0)                                                      \
        if (STAGE) { ST_B(nb_, 0, ktn); ST_B(nb_, 1, ktn); }                 \
        __builtin_amdgcn_s_barrier();                                        \
        MFMA_Q(0)                                                            \
        __builtin_amdgcn_s_barrier();                                        \
        LOAD_A(buf_, 1)                                                      \
        if (STAGE) { ST_B(nb_, 2, ktn); ST_B(nb_, 3, ktn); }                 \
        __builtin_amdgcn_s_barrier();                                        \
        MFMA_Q(1)                                                            \
        if (STAGE) { asm volatile("s_waitcnt vmcnt(4)" ::: "memory"); }      \
        else       { asm volatile("s_waitcnt vmcnt(0)" ::: "memory"); }      \
        __builtin_amdgcn_s_barrier();                                        \
        LOAD_A(buf_, 2)                                                      \
        if (STAGE) { ST_A(nb_, 0, ktn); ST_A(nb_, 2, ktn); }                 \
        __builtin_amdgcn_s_barrier();                                        \
        MFMA_Q(2)                                                            \
        __builtin_amdgcn_s_barrier();                                        \
        LOAD_A(buf_, 3)                                                      \
        if (STAGE) { ST_A(nb_, 1, ktn); ST_A(nb_, 3, ktn); }                 \
        __builtin_amdgcn_s_barrier();                                        \
        MFMA_Q(3)                                                            \
        if (STAGE) { asm volatile("s_waitcnt vmcnt(2)" ::: "memory"); }      \
        __builtin_amdgcn_s_barrier();                                        \
    }

    const int NT = Kd >> 6;
    for (int k = 0; k < NT - 1; ++k) {
        TILE(k & 1, true, (k + 1) << 6);
    }
    TILE((NT - 1) & 1, false, 0);

#undef TILE
#undef MFMA_Q
#undef LOAD_A
#undef READ_B
#undef ST_A
#undef ST_B

    const int r0 = lkg * 4;
    const size_t coff = (size_t)bz * (size_t)batchC;
#pragma unroll
    for (int ri = 0; ri < 8; ++ri) {
#pragma unroll
        for (int j = 0; j < 4; ++j) {
            if (EPI == 4) {
                if (qpath) {
                    const int gcol = bn + wc * 64 + j * 16 + lr;
                    const float bv = b0[gcol];
#pragma unroll
                    for (int r = 0; r < 4; ++r) {
                        const int grow = bm + wr * 128 + ri * 16 + r0 + r;
                        ((unsigned short*)C0)[(size_t)grow * 1024 + gcol] =
                            f2bf((acc[ri][j][r] + bv) * 0.03125f);
                    }
                } else {
                    const int gcol3 = bn + wc * 64 + j * 16 + lr;
                    const int which = gcol3 >> 10;
                    const int col   = gcol3 & 1023;
                    const float bv  = (which == 0) ? b1[col] : b2[col];
                    if (which == 0) {
                        unsigned short* dst = (unsigned short*)C1 + (size_t)bz * (2048 * 1024);
#pragma unroll
                        for (int r = 0; r < 4; ++r) {
                            const int grow = bm + wr * 128 + ri * 16 + r0 + r;
                            dst[(size_t)grow * 1024 + col] = f2bf(acc[ri][j][r] + bv);
                        }
                    } else {
                        const int m0 = bm + wr * 128 + ri * 16 + r0;
                        ushort4 wv;
                        wv.x = f2bf(acc[ri][j][0] + bv);
                        wv.y = f2bf(acc[ri][j][1] + bv);
                        wv.z = f2bf(acc[ri][j][2] + bv);
                        wv.w = f2bf(acc[ri][j][3] + bv);
                        *(ushort4*)((unsigned short*)C2 + (size_t)bz * (1024 * 2048)
                                    + (size_t)col * 2048 + m0) = wv;
                    }
                }
            } else if (EPI == 1) {
                const int gcol = bn + wc * 64 + j * 16 + lr;
#pragma unroll
                for (int r = 0; r < 4; ++r) {
                    const int grow = bm + wr * 128 + ri * 16 + r0 + r;
                    ((__half*)C0)[(size_t)bz * (2048 * 2048) + (size_t)grow * 2048 + gcol] =
                        __float2half(acc[ri][j][r]);
                }
            } else {
                const int gcol = bn + wc * 64 + j * 16 + lr;
#pragma unroll
                for (int r = 0; r < 4; ++r) {
                    const int grow = bm + wr * 128 + ri * 16 + r0 + r;
                    ((float*)C0)[coff + (size_t)grow * ldc + gcol] = acc[ri][j][r];
                }
            }
        }
    }
}

// 128x128-tile tail GEMM (m97-style single-buffer, 4 waves, T2 pre-swizzle).
// TEPI 0: KV-proj tail (gathered compact rows [1024,ncp), N=2048 K|V)
// TEPI 1: scores tail (cols [1024,ncp), fp16 out)
template<int TEPI>
__global__ __launch_bounds__(256)
void gemm_tail(const unsigned short* __restrict__ A, const unsigned short* __restrict__ B,
               void* __restrict__ C0, void* __restrict__ C1,
               const float* __restrict__ b0, const float* __restrict__ b1,
               const int* __restrict__ cidx, const int* __restrict__ ncinfo)
{
    __shared__ unsigned short As[128 * 64];
    __shared__ unsigned short Bs[128 * 64];

    int bid = blockIdx.x;
    bid = (bid & 7) * 32 + (bid >> 3);      // grid 256
    const int bz = bid >> 5;
    const int r  = bid & 31;
    int bm, bn;
    if (TEPI == 0) {
        bm = 1024 + (r >> 4) * 128;         // compact rows
        bn = (r & 15) * 128;                // 0..2047: K | V
        if (bm >= ncinfo[8 + bz]) return;
    } else {
        bm = (r >> 1) * 128;                // q rows (batch-local)
        bn = 1024 + (r & 1) * 128;          // score cols
        if (bn >= ncinfo[8 + bz]) return;
    }

    const int t    = threadIdx.x;
    const int lane = t & 63;
    const int w    = t >> 6;
    const int wm   = (w >> 1) * 64;
    const int wn   = (w & 1) * 64;
    const int lr   = lane & 15;
    const int lk8  = (lane >> 4) * 8;
    const int e0   = lk8 ^ ((lr & 7) * 8);  // T2 read-side

    const int srow = w * 8 + (lane >> 3);
    const int scol = (((lane & 7) ^ (srow & 7))) * 8;

    const unsigned short* Arow[4];
    const unsigned short* Brow[4];
#pragma unroll
    for (int p = 0; p < 4; ++p) {
        const int ra = bm + p * 32 + srow;
        const int rb = bn + p * 32 + srow;
        if (TEPI == 0) {
            const int rr = cidx[bz * 2048 + ra];
            Arow[p] = A + ((size_t)bz * 2048 + rr) * 1024 + scol;
            Brow[p] = B + (size_t)rb * 1024 + scol;              // Wk|Wv rows
        } else {
            Arow[p] = A + (size_t)bz * (2048 * 1024) + (size_t)ra * 1024 + scol;
            Brow[p] = B + (size_t)bz * (2048 * 1024) + (size_t)rb * 1024 + scol;
        }
    }

    f32x4 acc[4][4];
#pragma unroll
    for (int i = 0; i < 4; ++i)
#pragma unroll
        for (int j = 0; j < 4; ++j)
            acc[i][j] = f32x4{0.f, 0.f, 0.f, 0.f};

    for (int kt = 0; kt < 1024; kt += 64) {
#pragma unroll
        for (int p = 0; p < 4; ++p) {
            GLOAD_LDS16(Arow[p] + kt, &As[(p * 32 + w * 8) * 64]);
            GLOAD_LDS16(Brow[p] + kt, &Bs[(p * 32 + w * 8) * 64]);
        }
        asm volatile("s_waitcnt vmcnt(0)" ::: "memory");
        __builtin_amdgcn_s_barrier();

#pragma unroll
        for (int kk = 0; kk < 2; ++kk) {
            bf16x8 af[4], bfr[4];
#pragma unroll
            for (int i = 0; i < 4; ++i) {
                const int Ra = wm + i * 16 + lr;
                af[i] = *(const bf16x8*)&As[Ra * 64 + (kk ? (e0 ^ 32) : e0)];
            }
#pragma unroll
            for (int j = 0; j < 4; ++j) {
                const int Rb = wn + j * 16 + lr;
                bfr[j] = *(const bf16x8*)&Bs[Rb * 64 + (kk ? (e0 ^ 32) : e0)];
            }
#pragma unroll
            for (int i = 0; i < 4; ++i)
#pragma unroll
                for (int j = 0; j < 4; ++j)
                    acc[i][j] = __builtin_amdgcn_mfma_f32_16x16x32_bf16(af[i], bfr[j], acc[i][j], 0, 0, 0);
        }
        __builtin_amdgcn_s_barrier();
    }

    const int r0 = (lane >> 4) * 4;
#pragma unroll
    for (int i = 0; i < 4; ++i) {
#pragma unroll
        for (int j = 0; j < 4; ++j) {
            if (TEPI == 0) {
                const int gcol3 = bn + wn + j * 16 + lr;
                const int which = gcol3 >> 10;
                const int col   = gcol3 & 1023;
                const float bv  = (which == 0) ? b0[col] : b1[col];
                if (which == 0) {
                    unsigned short* dst = (unsigned short*)C0 + (size_t)bz * (2048 * 1024);
#pragma unroll
                    for (int rr = 0; rr < 4; ++rr) {
                        const int grow = bm + wm + i * 16 + r0 + rr;
                        dst[(size_t)grow * 1024 + col] = f2bf(acc[i][j][rr] + bv);
                    }
                } else {
                    const int m0 = bm + wm + i * 16 + r0;
                    ushort4 wv;
                    wv.x = f2bf(acc[i][j][0] + bv);
                    wv.y = f2bf(acc[i][j][1] + bv);
                    wv.z = f2bf(acc[i][j][2] + bv);
                    wv.w = f2bf(acc[i][j][3] + bv);
                    *(ushort4*)((unsigned short*)C1 + (size_t)bz * (1024 * 2048)
                                + (size_t)col * 2048 + m0) = wv;
                }
            } else {
                const int gcol = bn + wn + j * 16 + lr;
#pragma unroll
                for (int rr = 0; rr < 4; ++rr) {
                    const int grow = bm + wm + i * 16 + r0 + rr;
                    ((__half*)C0)[(size_t)bz * (2048 * 2048) + (size_t)grow * 2048 + gcol] =
                        __float2half(acc[i][j][rr]);
                }
            }
        }
    }
}

// Fused prep: x->bf16 (16384 blocks), Wq/Wk/Wv->bf16 (3x1024), compact (8).
// ncp now padded to 64 (floor 256); cidx zero-padded out to 1280 so tail
// tiles can stage full 128-row windows safely.
__global__ __launch_bounds__(256)
void prep(const float4* __restrict__ x, const float4* __restrict__ Wq,
          const float4* __restrict__ Wk, const float4* __restrict__ Wv,
          ushort4* __restrict__ xb, ushort4* __restrict__ wb,
          const int* __restrict__ mask, int* __restrict__ cidx,
          int* __restrict__ ncinfo)
{
    const int bidx = blockIdx.x;
    const int t = threadIdx.x;
    if (bidx < 19456) {
        const float4* src;
        ushort4* dst;
        int i;
        if (bidx < 16384)       { src = x;  dst = xb;               i = bidx * 256 + t; }
        else if (bidx < 17408)  { src = Wq; dst = wb;               i = (bidx - 16384) * 256 + t; }
        else if (bidx < 18432)  { src = Wk; dst = wb + 262144;      i = (bidx - 17408) * 256 + t; }
        else                    { src = Wv; dst = wb + 524288;      i = (bidx - 18432) * 256 + t; }
        const float4 v = src[i];
        ushort4 wv;
        wv.x = f2bf(v.x); wv.y = f2bf(v.y); wv.z = f2bf(v.z); wv.w = f2bf(v.w);
        dst[i] = wv;
        return;
    }
    // compact for batch b
    const int b = bidx - 19456;
    const int* mb = mask + b * 2048;
    int loc[8];
    int c = 0;
#pragma unroll
    for (int j = 0; j < 8; ++j) {
        const int s = t * 8 + j;
        if (mb[s] != 0) loc[c++] = s;
    }
    __shared__ int ps[256];
    ps[t] = c;
    __syncthreads();
    for (int off = 1; off < 256; off <<= 1) {
        const int v = (t >= off) ? ps[t - off] : 0;
        __syncthreads();
        ps[t] += v;
        __syncthreads();
    }
    const int base = ps[t] - c;
    int* cb = cidx + b * 2048;
    for (int i = 0; i < c; ++i) cb[base + i] = loc[i];
    __syncthreads();
    const int nc  = ps[255];
    int ncp = (nc + 63) & ~63;              // pad-64 (was pad-256)
    if (ncp < 256) ncp = 256;
    for (int i = nc + t; i < 1280; i += 256) cb[i] = 0;   // pad indices valid to 1280
    if (t == 0) { ncinfo[b] = nc; ncinfo[8 + b] = ncp; }
}

// Row softmax over compacted scores, IN-PLACE (fp16 in -> bf16 P out).
__global__ __launch_bounds__(256)
void softmax_rows(unsigned short* __restrict__ SP, const int* __restrict__ ncinfo)
{
    const size_t row = blockIdx.x;
    const int b   = (int)(row >> 11);
    const int nc  = ncinfo[b];
    const int ncp = ncinfo[8 + b];
    unsigned short* sp = SP + row * 2048;
    const int t  = threadIdx.x;
    const int c0 = t * 8;
    const bool act = c0 < ncp;

    float s[8];
#pragma unroll
    for (int j = 0; j < 8; ++j) s[j] = NEG_INF;
    if (act) {
        const ushort4 h0 = *(const ushort4*)&sp[c0];
        const ushort4 h1 = *(const ushort4*)&sp[c0 + 4];
        const unsigned short hv[8] = {h0.x, h0.y, h0.z, h0.w, h1.x, h1.y, h1.z, h1.w};
#pragma unroll
        for (int j = 0; j < 8; ++j)
            if (c0 + j < nc) s[j] = h2f(hv[j]);
    }

    float m = fmaxf(fmaxf(fmaxf(s[0], s[1]), fmaxf(s[2], s[3])),
                    fmaxf(fmaxf(s[4], s[5]), fmaxf(s[6], s[7])));

    __shared__ float red[256];
    red[t] = m;
    __syncthreads();
    for (int sw = 128; sw > 0; sw >>= 1) {
        if (t < sw) red[t] = fmaxf(red[t], red[t + sw]);
        __syncthreads();
    }
    const float mx = red[0];
    __syncthreads();

    float e[8];
#pragma unroll
    for (int j = 0; j < 8; ++j) e[j] = __expf(s[j] - mx);
    float s8 = ((e[0] + e[1]) + (e[2] + e[3])) + ((e[4] + e[5]) + (e[6] + e[7]));

    red[t] = s8;
    __syncthreads();
    for (int sw = 128; sw > 0; sw >>= 1) {
        if (t < sw) red[t] += red[t + sw];
        __syncthreads();
    }
    const float inv = 1.0f / red[0];

    if (act) {
        ushort4 w0, w1;
        w0.x = f2bf(e[0] * inv); w0.y = f2bf(e[1] * inv);
        w0.z = f2bf(e[2] * inv); w0.w = f2bf(e[3] * inv);
        w1.x = f2bf(e[4] * inv); w1.y = f2bf(e[5] * inv);
        w1.z = f2bf(e[6] * inv); w1.w = f2bf(e[7] * inv);
        *(ushort4*)&sp[c0]     = w0;
        *(ushort4*)&sp[c0 + 4] = w1;
    }
}

extern "C" void kernel_launch(void* const* d_in, const int* in_sizes, int n_in,
                              void* d_out, int out_size, void* d_ws, size_t ws_size,
                              hipStream_t stream)
{
    const float* x    = (const float*)d_in[0];
    const int*   mask = (const int*)d_in[1];
    const float* Wq   = (const float*)d_in[2];
    const float* bq   = (const float*)d_in[3];
    const float* Wk   = (const float*)d_in[4];
    const float* bk   = (const float*)d_in[5];
    const float* Wv   = (const float*)d_in[6];
    const float* bv   = (const float*)d_in[7];
    float* out = (float*)d_out;

    // Workspace (no live-range overlaps):
    //   [0,32)    Q   [16384][1024] bf16 (pre-scaled 1/32)
    //   [32,64)   Kc  [8][2048][1024] bf16 compact keys
    //   [64,96)   Vtc [8][1024][2048] bf16 compact V^T
    //   [96,160)  SP  [8][2048][2048] fp16 scores -> bf16 P in-place
    //   [160,192) xb  bf16 x
    //   [192,198) wb  bf16 weights [3072][1024]
    //   [198,199) cidx [8][2048]
    //   [199,..)  ncinfo [16]
    char* ws = (char*)d_ws;
    unsigned short* Q   = (unsigned short*)(ws);
    unsigned short* Kc  = (unsigned short*)(ws + (32ull << 20));
    unsigned short* Vtc = (unsigned short*)(ws + (64ull << 20));
    unsigned short* SP  = (unsigned short*)(ws + (96ull << 20));
    unsigned short* xb  = (unsigned short*)(ws + (160ull << 20));
    unsigned short* wb  = (unsigned short*)(ws + (192ull << 20));
    int*            cidx   = (int*)(ws + (198ull << 20));
    int*            ncinfo = (int*)(ws + (199ull << 20));

    const int D = 1024, S = 2048, B = 8;
    dim3 blk2(256), blk5(512);

    // ---- fused prep: conversions + compaction ----
    prep<<<dim3(19464), blk2, 0, stream>>>(
        (const float4*)x, (const float4*)Wq, (const float4*)Wk, (const float4*)Wv,
        (ushort4*)xb, (ushort4*)wb, mask, cidx, ncinfo);

    // ---- proj-main: Q (256 tiles) + KV compact rows [0,1024) (256 tiles) = 2 rounds ----
    gemm256<4><<<dim3(512), blk5, 0, stream>>>(
        xb, wb, Q, Kc, Vtc, bq, bk, bv, cidx, ncinfo,
        D, 1024, 1024, 1024, 0, 0, 0, 0, 0);

    // ---- proj-tail: KV compact rows [1024, ncp) (128^2 tiles) ----
    gemm_tail<0><<<dim3(256), blk2, 0, stream>>>(
        xb, wb + 1ull * D * D, Kc, Vtc, bk, bv, cidx, ncinfo);

    // ---- scores-main: cols [0,1024) (256 tiles = 1 round), fp16 out ----
    gemm256<1><<<dim3(256), blk5, 0, stream>>>(
        Q, Kc, SP, nullptr, nullptr, nullptr, nullptr, nullptr, cidx, ncinfo,
        D, 1024, 1024, 2048, (long)S * D, (long)S * D, (long)S * S, 0, 0);

    // ---- scores-tail: cols [1024, ncp) ----
    gemm_tail<1><<<dim3(256), blk2, 0, stream>>>(
        Q, Kc, SP, nullptr, nullptr, nullptr, cidx, ncinfo);

    // ---- softmax in-place ----
    softmax_rows<<<dim3(B * S), blk2, 0, stream>>>(SP, ncinfo);

    // ---- PV: O = P . Vtc^T (runtime K = ncp, now pad-64) ----
    gemm256<2><<<dim3(256), blk5, 0, stream>>>(
        SP, Vtc, out, nullptr, nullptr, nullptr, nullptr, nullptr, cidx, ncinfo,
        S, 2048, 2048, 1024, (long)S * 2048, (long)D * S, (long)S * D, 8, 4);
}